// Round 5
// baseline (290.279 us; speedup 1.0000x reference)
//
#include <hip/hip_runtime.h>

#define FDIM 512

__device__ __forceinline__ float4 ld4(const float* p) { return *(const float4*)p; }

// Fused per-batch kernel. One block = one batch (256 blocks on 256 CUs,
// 16 waves each). Wave w owns rows [32w, 32w+32), processed in 8 groups of
// 4 rows with a 2-buffer software pipeline (8 float4 loads issued one full
// group ahead). No barriers in the streaming loops.
// __launch_bounds__(1024, 4): block = 16 waves = 4 waves/SIMD -> VGPR cap
// 512/4 = 128. Without the "4" the compiler targeted 64 VGPR and spilled
// the pipeline buffers to scratch (round-4 post-mortem: +230 MB FETCH,
// +300 MB WRITE of pure spill traffic).
__global__ __launch_bounds__(1024, 4)
void rvsoftmax_deep(const float* __restrict__ mu,
                    const float* __restrict__ Sigma,
                    float* __restrict__ p_out,
                    float* __restrict__ S_out) {
    const int b = blockIdx.x;
    const int t = threadIdx.x;
    const int w = t >> 6;   // wave 0..15
    const int l = t & 63;   // lane 0..63

    __shared__ __align__(16) float p_lds[FDIM];
    __shared__ __align__(16) float r_lds[FDIM];
    __shared__ __align__(16) float c_lds[FDIM];
    __shared__ __align__(16) float cst[16][FDIM];   // 32 KB c-partial stage
    __shared__ float red[16];
    __shared__ float sc[2];

    const float* Sb = Sigma + (size_t)b * FDIM * FDIM;
    float* Ob       = S_out + (size_t)b * FDIM * FDIM;
    const int i0 = w * 32;
    const float* base = Sb + (size_t)i0 * FDIM + 4 * l;

    float4 A[8], B[8];

#define LOADG(arr, g) do {                                                  \
    const float* gp_ = base + (size_t)(g) * 4 * FDIM;                       \
    _Pragma("unroll")                                                       \
    for (int q_ = 0; q_ < 4; ++q_) {                                        \
        arr[2*q_]   = ld4(gp_ + q_ * FDIM);                                 \
        arr[2*q_+1] = ld4(gp_ + q_ * FDIM + 256);                           \
    } } while (0)

    // Issue two groups' loads immediately — they fly during the softmax.
    LOADG(A, 0);
    LOADG(B, 1);

    // ---------------- softmax over mu[b,:] ----------------
    float x = (t < FDIM) ? mu[(size_t)b * FDIM + t] : -__builtin_inff();
    float m = x;
    #pragma unroll
    for (int off = 32; off >= 1; off >>= 1) m = fmaxf(m, __shfl_xor(m, off));
    if (l == 0) red[w] = m;
    __syncthreads();
    if (t == 0) {
        float mm = red[0];
        for (int j = 1; j < 16; ++j) mm = fmaxf(mm, red[j]);
        sc[0] = mm;
    }
    __syncthreads();
    const float mx = sc[0];
    float e = (t < FDIM) ? __expf(x - mx) : 0.f;
    float ssum = e;
    #pragma unroll
    for (int off = 32; off >= 1; off >>= 1) ssum += __shfl_xor(ssum, off);
    if (l == 0) red[w] = ssum;
    __syncthreads();
    if (t == 0) {
        float tt = 0.f;
        for (int j = 0; j < 16; ++j) tt += red[j];
        sc[0] = tt;
    }
    __syncthreads();
    const float inv = 1.0f / sc[0];
    if (t < FDIM) {
        float pv = e * inv;
        p_lds[t] = pv;
        p_out[(size_t)b * FDIM + t] = pv;
    }
    __syncthreads();

    const float4 p0 = ld4(&p_lds[4 * l]);
    const float4 p1 = ld4(&p_lds[256 + 4 * l]);

    // ---------------- Phase 1: r_i and c-partials, barrier-free ---------
    float4 c0 = make_float4(0.f, 0.f, 0.f, 0.f);
    float4 c1 = make_float4(0.f, 0.f, 0.f, 0.f);

#define COMP1(arr, g) do {                                                  \
    _Pragma("unroll")                                                       \
    for (int q_ = 0; q_ < 4; ++q_) {                                        \
        const int i_ = i0 + (g) * 4 + q_;                                   \
        const float4 x0 = arr[2*q_], x1 = arr[2*q_+1];                      \
        float dot = x0.x*p0.x + x0.y*p0.y + x0.z*p0.z + x0.w*p0.w          \
                  + x1.x*p1.x + x1.y*p1.y + x1.z*p1.z + x1.w*p1.w;         \
        _Pragma("unroll")                                                   \
        for (int o_ = 32; o_ >= 1; o_ >>= 1) dot += __shfl_xor(dot, o_);    \
        if (l == 0) r_lds[i_] = dot;                                        \
        const float pi_ = p_lds[i_];                                        \
        c0.x += pi_*x0.x; c0.y += pi_*x0.y; c0.z += pi_*x0.z; c0.w += pi_*x0.w; \
        c1.x += pi_*x1.x; c1.y += pi_*x1.y; c1.z += pi_*x1.z; c1.w += pi_*x1.w; \
    } } while (0)

    COMP1(A, 0); LOADG(A, 2);
    COMP1(B, 1); LOADG(B, 3);
    COMP1(A, 2); LOADG(A, 4);
    COMP1(B, 3); LOADG(B, 5);
    COMP1(A, 4); LOADG(A, 6);
    COMP1(B, 5); LOADG(B, 7);
    COMP1(A, 6);
    COMP1(B, 7);

    // ---------------- Mid: reduce c-partials, compute s ------------------
    *(float4*)&cst[w][4 * l] = c0;
    *(float4*)&cst[w][256 + 4 * l] = c1;
    // Prefetch phase-2's first two groups (L2/L3-hot: just read) across
    // the reduction barriers.
    LOADG(A, 7);
    LOADG(B, 6);
    __syncthreads();
    if (t < FDIM) {
        float cc = 0.f;
        #pragma unroll
        for (int j = 0; j < 16; ++j) cc += cst[j][t];
        c_lds[t] = cc;
    }
    float sv = (t < FDIM) ? p_lds[t] * r_lds[t] : 0.f;
    #pragma unroll
    for (int off = 32; off >= 1; off >>= 1) sv += __shfl_xor(sv, off);
    if (l == 0) red[w] = sv;
    __syncthreads();
    if (t == 0) {
        float tt = 0.f;
        for (int j = 0; j < 16; ++j) tt += red[j];
        sc[1] = tt;
    }
    __syncthreads();
    const float s = sc[1];
    const float4 cc0 = ld4(&c_lds[4 * l]);
    const float4 cc1 = ld4(&c_lds[256 + 4 * l]);

    // ---------------- Phase 2: out = p_i p_k (Sigma + (s-r_i) - c_k) ----
    // Reverse group order (rows just read are re-read first -> L2/L3 hot).
#define COMP2(arr, g) do {                                                  \
    _Pragma("unroll")                                                       \
    for (int q_ = 0; q_ < 4; ++q_) {                                        \
        const int i_ = i0 + (g) * 4 + q_;                                   \
        const float4 x0 = arr[2*q_], x1 = arr[2*q_+1];                      \
        const float pi_ = p_lds[i_];                                        \
        const float f_ = s - r_lds[i_];                                     \
        float4 o0, o1;                                                      \
        o0.x = pi_*p0.x*(x0.x + (f_ - cc0.x));                              \
        o0.y = pi_*p0.y*(x0.y + (f_ - cc0.y));                              \
        o0.z = pi_*p0.z*(x0.z + (f_ - cc0.z));                              \
        o0.w = pi_*p0.w*(x0.w + (f_ - cc0.w));                              \
        o1.x = pi_*p1.x*(x1.x + (f_ - cc1.x));                              \
        o1.y = pi_*p1.y*(x1.y + (f_ - cc1.y));                              \
        o1.z = pi_*p1.z*(x1.z + (f_ - cc1.z));                              \
        o1.w = pi_*p1.w*(x1.w + (f_ - cc1.w));                              \
        float* op_ = Ob + (size_t)i_ * FDIM + 4 * l;                        \
        *(float4*)op_ = o0;                                                 \
        *(float4*)(op_ + 256) = o1;                                         \
    } } while (0)

    COMP2(A, 7); LOADG(A, 5);
    COMP2(B, 6); LOADG(B, 4);
    COMP2(A, 5); LOADG(A, 3);
    COMP2(B, 4); LOADG(B, 2);
    COMP2(A, 3); LOADG(A, 1);
    COMP2(B, 2); LOADG(B, 0);
    COMP2(A, 1);
    COMP2(B, 0);

#undef LOADG
#undef COMP1
#undef COMP2
}

extern "C" void kernel_launch(void* const* d_in, const int* in_sizes, int n_in,
                              void* d_out, int out_size, void* d_ws, size_t ws_size,
                              hipStream_t stream) {
    (void)in_sizes; (void)n_in; (void)out_size; (void)d_ws; (void)ws_size;
    const float* mu    = (const float*)d_in[0];
    const float* Sigma = (const float*)d_in[1];
    float* p_out = (float*)d_out;
    float* S_out = (float*)d_out + (size_t)256 * 512;
    hipLaunchKernelGGL(rvsoftmax_deep, dim3(256), dim3(1024), 0, stream,
                       mu, Sigma, p_out, S_out);
}

// Round 6
// 266.928 us; speedup vs baseline: 1.0875x; 1.0875x over previous
//
#include <hip/hip_runtime.h>

#define FDIM 512

__device__ __forceinline__ float4 ld4(const float* p) { return *(const float4*)p; }

// Fused per-batch kernel. One block = one batch (256 blocks, 16 waves each).
// Wave w owns rows [32w, 32w+32) in 8 groups of 4 rows, 2-group software
// pipeline held in SIXTEEN NAMED float4 registers (A0..A7, B0..B7) — no
// arrays, so nothing can fall to scratch (round-4/5 post-mortem: float4
// arr[8] failed SROA -> scratch -> +230/+300 MB spill traffic, VGPR=64).
__global__ __launch_bounds__(1024, 4)
void rvsoftmax_deep(const float* __restrict__ mu,
                    const float* __restrict__ Sigma,
                    float* __restrict__ p_out,
                    float* __restrict__ S_out) {
    const int b = blockIdx.x;
    const int t = threadIdx.x;
    const int w = t >> 6;   // wave 0..15
    const int l = t & 63;   // lane 0..63

    __shared__ __align__(16) float p_lds[FDIM];
    __shared__ __align__(16) float r_lds[FDIM];
    __shared__ __align__(16) float c_lds[FDIM];
    __shared__ __align__(16) float cst[16][FDIM];
    __shared__ float red[16];
    __shared__ float sc[2];

    const float* Sb = Sigma + (size_t)b * FDIM * FDIM;
    float* Ob       = S_out + (size_t)b * FDIM * FDIM;
    const int i0 = w * 32;
    const float* base = Sb + (size_t)i0 * FDIM + 4 * l;

    float4 A0, A1, A2, A3, A4, A5, A6, A7;
    float4 B0, B1, B2, B3, B4, B5, B6, B7;

#define LOADG(P, g) do {                                                    \
    const float* gp_ = base + (size_t)(g) * 4 * FDIM;                       \
    P##0 = ld4(gp_);              P##1 = ld4(gp_ + 256);                    \
    P##2 = ld4(gp_ + FDIM);       P##3 = ld4(gp_ + FDIM + 256);             \
    P##4 = ld4(gp_ + 2 * FDIM);   P##5 = ld4(gp_ + 2 * FDIM + 256);         \
    P##6 = ld4(gp_ + 3 * FDIM);   P##7 = ld4(gp_ + 3 * FDIM + 256);         \
} while (0)

    // Issue two groups' loads immediately — they fly during the softmax.
    LOADG(A, 0);
    LOADG(B, 1);

    // ---------------- softmax over mu[b,:] ----------------
    float x = (t < FDIM) ? mu[(size_t)b * FDIM + t] : -__builtin_inff();
    float m = x;
    #pragma unroll
    for (int off = 32; off >= 1; off >>= 1) m = fmaxf(m, __shfl_xor(m, off));
    if (l == 0) red[w] = m;
    __syncthreads();
    if (t == 0) {
        float mm = red[0];
        for (int j = 1; j < 16; ++j) mm = fmaxf(mm, red[j]);
        sc[0] = mm;
    }
    __syncthreads();
    const float mx = sc[0];
    float e = (t < FDIM) ? __expf(x - mx) : 0.f;
    float ssum = e;
    #pragma unroll
    for (int off = 32; off >= 1; off >>= 1) ssum += __shfl_xor(ssum, off);
    if (l == 0) red[w] = ssum;
    __syncthreads();
    if (t == 0) {
        float tt = 0.f;
        for (int j = 0; j < 16; ++j) tt += red[j];
        sc[0] = tt;
    }
    __syncthreads();
    const float inv = 1.0f / sc[0];
    if (t < FDIM) {
        float pv = e * inv;
        p_lds[t] = pv;
        p_out[(size_t)b * FDIM + t] = pv;
    }
    __syncthreads();

    const float4 p0 = ld4(&p_lds[4 * l]);
    const float4 p1 = ld4(&p_lds[256 + 4 * l]);

    // ---------------- Phase 1: r_i and c-partials, barrier-free ---------
    float4 c0 = make_float4(0.f, 0.f, 0.f, 0.f);
    float4 c1 = make_float4(0.f, 0.f, 0.f, 0.f);

#define ROW1(x0, x1, i_) do {                                               \
    float dot = x0.x*p0.x + x0.y*p0.y + x0.z*p0.z + x0.w*p0.w              \
              + x1.x*p1.x + x1.y*p1.y + x1.z*p1.z + x1.w*p1.w;             \
    _Pragma("unroll")                                                       \
    for (int o_ = 32; o_ >= 1; o_ >>= 1) dot += __shfl_xor(dot, o_);        \
    if (l == 0) r_lds[i_] = dot;                                            \
    const float pi_ = p_lds[i_];                                            \
    c0.x += pi_*x0.x; c0.y += pi_*x0.y; c0.z += pi_*x0.z; c0.w += pi_*x0.w; \
    c1.x += pi_*x1.x; c1.y += pi_*x1.y; c1.z += pi_*x1.z; c1.w += pi_*x1.w; \
} while (0)

#define COMP1(P, g) do {                                                    \
    ROW1(P##0, P##1, i0 + (g) * 4 + 0);                                     \
    ROW1(P##2, P##3, i0 + (g) * 4 + 1);                                     \
    ROW1(P##4, P##5, i0 + (g) * 4 + 2);                                     \
    ROW1(P##6, P##7, i0 + (g) * 4 + 3);                                     \
} while (0)

    COMP1(A, 0); LOADG(A, 2);
    COMP1(B, 1); LOADG(B, 3);
    COMP1(A, 2); LOADG(A, 4);
    COMP1(B, 3); LOADG(B, 5);
    COMP1(A, 4); LOADG(A, 6);
    COMP1(B, 5); LOADG(B, 7);
    COMP1(A, 6);
    COMP1(B, 7);

    // ---------------- Mid: reduce c-partials, compute s ------------------
    *(float4*)&cst[w][4 * l] = c0;
    *(float4*)&cst[w][256 + 4 * l] = c1;
    // Prefetch phase-2's first two groups (L2/L3-hot) across the barriers.
    LOADG(A, 7);
    LOADG(B, 6);
    __syncthreads();
    if (t < FDIM) {
        float cc = 0.f;
        #pragma unroll
        for (int j = 0; j < 16; ++j) cc += cst[j][t];
        c_lds[t] = cc;
    }
    float sv = (t < FDIM) ? p_lds[t] * r_lds[t] : 0.f;
    #pragma unroll
    for (int off = 32; off >= 1; off >>= 1) sv += __shfl_xor(sv, off);
    if (l == 0) red[w] = sv;
    __syncthreads();
    if (t == 0) {
        float tt = 0.f;
        for (int j = 0; j < 16; ++j) tt += red[j];
        sc[1] = tt;
    }
    __syncthreads();
    const float s = sc[1];
    const float4 cc0 = ld4(&c_lds[4 * l]);
    const float4 cc1 = ld4(&c_lds[256 + 4 * l]);

    // ---------------- Phase 2: out = p_i p_k (Sigma + (s-r_i) - c_k) ----
    // Reverse group order (rows just read are re-read first -> L2/L3 hot).
#define ROW2(x0, x1, i_) do {                                               \
    const float pi_ = p_lds[i_];                                            \
    const float f_ = s - r_lds[i_];                                         \
    float4 o0, o1;                                                          \
    o0.x = pi_*p0.x*(x0.x + (f_ - cc0.x));                                  \
    o0.y = pi_*p0.y*(x0.y + (f_ - cc0.y));                                  \
    o0.z = pi_*p0.z*(x0.z + (f_ - cc0.z));                                  \
    o0.w = pi_*p0.w*(x0.w + (f_ - cc0.w));                                  \
    o1.x = pi_*p1.x*(x1.x + (f_ - cc1.x));                                  \
    o1.y = pi_*p1.y*(x1.y + (f_ - cc1.y));                                  \
    o1.z = pi_*p1.z*(x1.z + (f_ - cc1.z));                                  \
    o1.w = pi_*p1.w*(x1.w + (f_ - cc1.w));                                  \
    float* op_ = Ob + (size_t)(i_) * FDIM + 4 * l;                          \
    *(float4*)op_ = o0;                                                     \
    *(float4*)(op_ + 256) = o1;                                             \
} while (0)

#define COMP2(P, g) do {                                                    \
    ROW2(P##0, P##1, i0 + (g) * 4 + 0);                                     \
    ROW2(P##2, P##3, i0 + (g) * 4 + 1);                                     \
    ROW2(P##4, P##5, i0 + (g) * 4 + 2);                                     \
    ROW2(P##6, P##7, i0 + (g) * 4 + 3);                                     \
} while (0)

    COMP2(A, 7); LOADG(A, 5);
    COMP2(B, 6); LOADG(B, 4);
    COMP2(A, 5); LOADG(A, 3);
    COMP2(B, 4); LOADG(B, 2);
    COMP2(A, 3); LOADG(A, 1);
    COMP2(B, 2); LOADG(B, 0);
    COMP2(A, 1);
    COMP2(B, 0);

#undef LOADG
#undef ROW1
#undef COMP1
#undef ROW2
#undef COMP2
}

extern "C" void kernel_launch(void* const* d_in, const int* in_sizes, int n_in,
                              void* d_out, int out_size, void* d_ws, size_t ws_size,
                              hipStream_t stream) {
    (void)in_sizes; (void)n_in; (void)out_size; (void)d_ws; (void)ws_size;
    const float* mu    = (const float*)d_in[0];
    const float* Sigma = (const float*)d_in[1];
    float* p_out = (float*)d_out;
    float* S_out = (float*)d_out + (size_t)256 * 512;
    hipLaunchKernelGGL(rvsoftmax_deep, dim3(256), dim3(1024), 0, stream,
                       mu, Sigma, p_out, S_out);
}

// Round 8
// 136.938 us; speedup vs baseline: 2.1198x; 1.9493x over previous
//
#include <hip/hip_runtime.h>

#define FDIM 512
#define S_ELEMS (FDIM * FDIM)

// ---------------- ws layout (floats) ----------------
#define R_OFF      0                    // r[256][512]
#define C_OFF      131072               // c[256][512]
#define S_OFF      262144               // s[256]
#define CP_OFF     262400               // c_part[256*8][512]
#define WS_FLOATS  (262400 + 256 * 8 * 512)

__device__ __forceinline__ float4 ld4(const float* p) { return *(const float4*)p; }

typedef float vf4 __attribute__((ext_vector_type(4)));
__device__ __forceinline__ void st4nt(float* p, float4 v) {
    __builtin_nontemporal_store(*(vf4*)&v, (vf4*)p);
}

// ======================= K1: p, r, c-partials (pure read) ==============
// grid 2048 = 256 batches x 8 slabs(64 rows). block 256 thr = 4 waves.
// Wave w streams 16 rows with a 4-row-deep named-register pipeline.
__global__ __launch_bounds__(256)
void k1_rc(const float* __restrict__ mu,
           const float* __restrict__ Sigma,
           float* __restrict__ p_out,
           float* __restrict__ ws) {
    const int bid  = blockIdx.x;
    const int b    = bid >> 3;
    const int slab = bid & 7;
    const int t = threadIdx.x;
    const int w = t >> 6;
    const int l = t & 63;

    __shared__ __align__(16) float p_lds[FDIM];
    __shared__ __align__(16) float cred[4][FDIM];
    __shared__ float red[4];
    __shared__ float sc[1];

    // --- softmax p[b,:], 2 elems/thread ---
    const float x0 = mu[(size_t)b * FDIM + t];
    const float x1 = mu[(size_t)b * FDIM + t + 256];
    float m = fmaxf(x0, x1);
    #pragma unroll
    for (int off = 32; off >= 1; off >>= 1) m = fmaxf(m, __shfl_xor(m, off));
    if (l == 0) red[w] = m;
    __syncthreads();
    if (t == 0) sc[0] = fmaxf(fmaxf(red[0], red[1]), fmaxf(red[2], red[3]));
    __syncthreads();
    const float mx = sc[0];
    const float e0 = __expf(x0 - mx);
    const float e1 = __expf(x1 - mx);
    float ssum = e0 + e1;
    #pragma unroll
    for (int off = 32; off >= 1; off >>= 1) ssum += __shfl_xor(ssum, off);
    if (l == 0) red[w] = ssum;
    __syncthreads();
    if (t == 0) sc[0] = red[0] + red[1] + red[2] + red[3];
    __syncthreads();
    const float inv = 1.0f / sc[0];
    const float pva = e0 * inv, pvb = e1 * inv;
    p_lds[t] = pva;
    p_lds[t + 256] = pvb;
    if (slab == 0) {
        p_out[(size_t)b * FDIM + t] = pva;
        p_out[(size_t)b * FDIM + t + 256] = pvb;
    }
    __syncthreads();

    const float4 p0 = ld4(&p_lds[4 * l]);
    const float4 p1 = ld4(&p_lds[256 + 4 * l]);

    const int i0 = slab * 64 + w * 16;                 // first global row
    const float* base = Sigma + (size_t)b * S_ELEMS + (size_t)i0 * FDIM + 4 * l;
    float* r_ws = ws + R_OFF + (size_t)b * FDIM;

    float4 c0 = make_float4(0.f, 0.f, 0.f, 0.f);
    float4 c1 = make_float4(0.f, 0.f, 0.f, 0.f);
    float4 A0, A1, B0, B1, C0, C1, D0, D1;

#define LD1(P, q) do { const float* gp_ = base + (size_t)(q) * FDIM;        \
    P##0 = ld4(gp_); P##1 = ld4(gp_ + 256); } while (0)

#define RCROW(v0, v1, q) do {                                               \
    const int i_ = i0 + (q);                                                \
    float dot = v0.x*p0.x + v0.y*p0.y + v0.z*p0.z + v0.w*p0.w               \
              + v1.x*p1.x + v1.y*p1.y + v1.z*p1.z + v1.w*p1.w;              \
    _Pragma("unroll")                                                       \
    for (int o_ = 32; o_ >= 1; o_ >>= 1) dot += __shfl_xor(dot, o_);        \
    if (l == 0) r_ws[i_] = dot;                                             \
    const float pi_ = p_lds[i_];                                            \
    c0.x += pi_*v0.x; c0.y += pi_*v0.y; c0.z += pi_*v0.z; c0.w += pi_*v0.w; \
    c1.x += pi_*v1.x; c1.y += pi_*v1.y; c1.z += pi_*v1.z; c1.w += pi_*v1.w; \
} while (0)
#define RC1(P, q) RCROW(P##0, P##1, q)

    LD1(A, 0); LD1(B, 1); LD1(C, 2);
    RC1(A, 0);  LD1(D, 3);
    RC1(B, 1);  LD1(A, 4);
    RC1(C, 2);  LD1(B, 5);
    RC1(D, 3);  LD1(C, 6);
    RC1(A, 4);  LD1(D, 7);
    RC1(B, 5);  LD1(A, 8);
    RC1(C, 6);  LD1(B, 9);
    RC1(D, 7);  LD1(C, 10);
    RC1(A, 8);  LD1(D, 11);
    RC1(B, 9);  LD1(A, 12);
    RC1(C, 10); LD1(B, 13);
    RC1(D, 11); LD1(C, 14);
    RC1(A, 12); LD1(D, 15);
    RC1(B, 13);
    RC1(C, 14);
    RC1(D, 15);
#undef LD1
#undef RCROW
#undef RC1

    // --- reduce c partials across the 4 waves ---
    *(float4*)&cred[w][4 * l] = c0;
    *(float4*)&cred[w][256 + 4 * l] = c1;
    __syncthreads();
    const float ca = cred[0][t] + cred[1][t] + cred[2][t] + cred[3][t];
    const float cb = cred[0][t + 256] + cred[1][t + 256] + cred[2][t + 256] + cred[3][t + 256];
    float* cp = ws + CP_OFF + ((size_t)b * 8 + slab) * FDIM;
    cp[t] = ca;
    cp[t + 256] = cb;
}

// ======================= K2b: c reduce + s =======================
__global__ __launch_bounds__(512)
void k2b_cs(const float* __restrict__ p_out, float* __restrict__ ws) {
    const int b = blockIdx.x;
    const int t = threadIdx.x;
    const int w = t >> 6;
    const int l = t & 63;
    __shared__ float red[8];

    float cc = 0.f;
    #pragma unroll
    for (int j = 0; j < 8; ++j)
        cc += ws[CP_OFF + ((size_t)b * 8 + j) * FDIM + t];
    ws[C_OFF + (size_t)b * FDIM + t] = cc;

    float sv = p_out[(size_t)b * FDIM + t] * ws[R_OFF + (size_t)b * FDIM + t];
    #pragma unroll
    for (int off = 32; off >= 1; off >>= 1) sv += __shfl_xor(sv, off);
    if (l == 0) red[w] = sv;
    __syncthreads();
    if (t == 0) {
        float tt = 0.f;
        for (int j = 0; j < 8; ++j) tt += red[j];
        ws[S_OFF + b] = tt;
    }
}

// ======================= K3: output stream (reverse, NT stores) ========
// grid 2048 REVERSED; block 256 thr = 4 waves, 16 rows/wave.
__global__ __launch_bounds__(256)
void k3_out(const float* __restrict__ Sigma,
            const float* __restrict__ p_out,
            const float* __restrict__ ws,
            float* __restrict__ S_out) {
    const int bid  = 2047 - (int)blockIdx.x;   // reverse global sweep
    const int b    = bid >> 3;
    const int slab = bid & 7;
    const int t = threadIdx.x;
    const int w = t >> 6;
    const int l = t & 63;

    __shared__ float pr[64], rr[64];
    if (t < 64) {
        pr[t] = p_out[(size_t)b * FDIM + slab * 64 + t];
        rr[t] = ws[R_OFF + (size_t)b * FDIM + slab * 64 + t];
    }
    const float4 p0 = ld4(p_out + (size_t)b * FDIM + 4 * l);
    const float4 p1 = ld4(p_out + (size_t)b * FDIM + 256 + 4 * l);
    const float4 c0 = ld4(ws + C_OFF + (size_t)b * FDIM + 4 * l);
    const float4 c1 = ld4(ws + C_OFF + (size_t)b * FDIM + 256 + 4 * l);
    const float  s  = ws[S_OFF + b];
    __syncthreads();

    const int i0 = slab * 64 + w * 16;
    const float* base = Sigma + (size_t)b * S_ELEMS + (size_t)i0 * FDIM + 4 * l;
    float* obase      = S_out + (size_t)b * S_ELEMS + (size_t)i0 * FDIM + 4 * l;

    float4 A0, A1, B0, B1, C0, C1, D0, D1;

#define LD3(P, q) do { const float* gp_ = base + (size_t)(q) * FDIM;        \
    P##0 = ld4(gp_); P##1 = ld4(gp_ + 256); } while (0)

#define OWROW(v0, v1, q) do {                                               \
    const int lr_ = w * 16 + (q);                                           \
    const float pi_ = pr[lr_];                                              \
    const float f_  = s - rr[lr_];                                          \
    float4 o0, o1;                                                          \
    o0.x = pi_*p0.x*(v0.x + (f_ - c0.x));                                   \
    o0.y = pi_*p0.y*(v0.y + (f_ - c0.y));                                   \
    o0.z = pi_*p0.z*(v0.z + (f_ - c0.z));                                   \
    o0.w = pi_*p0.w*(v0.w + (f_ - c0.w));                                   \
    o1.x = pi_*p1.x*(v1.x + (f_ - c1.x));                                   \
    o1.y = pi_*p1.y*(v1.y + (f_ - c1.y));                                   \
    o1.z = pi_*p1.z*(v1.z + (f_ - c1.z));                                   \
    o1.w = pi_*p1.w*(v1.w + (f_ - c1.w));                                   \
    float* op_ = obase + (size_t)(q) * FDIM;                                \
    st4nt(op_, o0); st4nt(op_ + 256, o1);                                   \
} while (0)
#define OW3(P, q) OWROW(P##0, P##1, q)

    LD3(A, 0); LD3(B, 1); LD3(C, 2);
    OW3(A, 0);  LD3(D, 3);
    OW3(B, 1);  LD3(A, 4);
    OW3(C, 2);  LD3(B, 5);
    OW3(D, 3);  LD3(C, 6);
    OW3(A, 4);  LD3(D, 7);
    OW3(B, 5);  LD3(A, 8);
    OW3(C, 6);  LD3(B, 9);
    OW3(D, 7);  LD3(C, 10);
    OW3(A, 8);  LD3(D, 11);
    OW3(B, 9);  LD3(A, 12);
    OW3(C, 10); LD3(B, 13);
    OW3(D, 11); LD3(C, 14);
    OW3(A, 12); LD3(D, 15);
    OW3(B, 13);
    OW3(C, 14);
    OW3(D, 15);
#undef LD3
#undef OWROW
#undef OW3
}

// ======================= fallback: round-1 fused (proven 157 us) ========
__global__ __launch_bounds__(1024, 1)
void rvsoftmax_fused(const float* __restrict__ mu,
                     const float* __restrict__ Sigma,
                     float* __restrict__ p_out,
                     float* __restrict__ S_out) {
    const int b = blockIdx.x, t = threadIdx.x, w = t >> 6, l = t & 63;
    __shared__ __align__(16) float p_lds[FDIM];
    __shared__ __align__(16) float r_lds[FDIM];
    __shared__ __align__(16) float c_lds[FDIM];
    __shared__ __align__(16) float c_stage[16][FDIM];
    __shared__ float red[16]; __shared__ float sc[2];
    float x = (t < FDIM) ? mu[(size_t)b * FDIM + t] : -__builtin_inff();
    float m = x;
    #pragma unroll
    for (int off = 32; off >= 1; off >>= 1) m = fmaxf(m, __shfl_xor(m, off));
    if (l == 0) red[w] = m;
    __syncthreads();
    if (t == 0) { float mm = red[0]; for (int j = 1; j < 16; ++j) mm = fmaxf(mm, red[j]); sc[0] = mm; }
    __syncthreads();
    const float mx = sc[0];
    float e = (t < FDIM) ? __expf(x - mx) : 0.f;
    float ssum = e;
    #pragma unroll
    for (int off = 32; off >= 1; off >>= 1) ssum += __shfl_xor(ssum, off);
    if (l == 0) red[w] = ssum;
    __syncthreads();
    if (t == 0) { float tt = 0.f; for (int j = 0; j < 16; ++j) tt += red[j]; sc[0] = tt; }
    __syncthreads();
    const float inv = 1.0f / sc[0];
    if (t < FDIM) { float pv = e * inv; p_lds[t] = pv; p_out[(size_t)b * FDIM + t] = pv; }
    __syncthreads();
    const float* Sb = Sigma + (size_t)b * S_ELEMS;
    const float4 p0 = ld4(&p_lds[4 * l]);
    const float4 p1 = ld4(&p_lds[256 + 4 * l]);
    float4 c0 = make_float4(0.f, 0.f, 0.f, 0.f), c1 = make_float4(0.f, 0.f, 0.f, 0.f);
    for (int j = 0; j < 32; ++j) {
        const int i = j * 16 + w;
        const float* row = Sb + (size_t)i * FDIM;
        const float4 a0 = ld4(&row[4 * l]); const float4 a1 = ld4(&row[256 + 4 * l]);
        const float pi = p_lds[i];
        float dot = a0.x*p0.x + a0.y*p0.y + a0.z*p0.z + a0.w*p0.w
                  + a1.x*p1.x + a1.y*p1.y + a1.z*p1.z + a1.w*p1.w;
        #pragma unroll
        for (int off = 32; off >= 1; off >>= 1) dot += __shfl_xor(dot, off);
        if (l == 0) r_lds[i] = dot;
        c0.x += pi*a0.x; c0.y += pi*a0.y; c0.z += pi*a0.z; c0.w += pi*a0.w;
        c1.x += pi*a1.x; c1.y += pi*a1.y; c1.z += pi*a1.z; c1.w += pi*a1.w;
    }
    *(float4*)&c_stage[w][4 * l] = c0;
    *(float4*)&c_stage[w][256 + 4 * l] = c1;
    __syncthreads();
    if (t < FDIM) {
        float cc = 0.f;
        #pragma unroll
        for (int j = 0; j < 16; ++j) cc += c_stage[j][t];
        c_lds[t] = cc;
    }
    __syncthreads();
    float sv = (t < FDIM) ? p_lds[t] * r_lds[t] : 0.f;
    #pragma unroll
    for (int off = 32; off >= 1; off >>= 1) sv += __shfl_xor(sv, off);
    if (l == 0) red[w] = sv;
    __syncthreads();
    if (t == 0) { float tt = 0.f; for (int j = 0; j < 16; ++j) tt += red[j]; sc[1] = tt; }
    __syncthreads();
    const float s = sc[1];
    const float4 cc0 = ld4(&c_lds[4 * l]); const float4 cc1 = ld4(&c_lds[256 + 4 * l]);
    float* Ob = S_out + (size_t)b * S_ELEMS;
    for (int j = 31; j >= 0; --j) {
        const int i = j * 16 + w;
        const float* row = Sb + (size_t)i * FDIM;
        float* orow = Ob + (size_t)i * FDIM;
        const float4 a0 = ld4(&row[4 * l]); const float4 a1 = ld4(&row[256 + 4 * l]);
        const float pi = p_lds[i];
        const float f = s - r_lds[i];
        float4 o0, o1;
        o0.x = pi*p0.x*(a0.x + (f - cc0.x)); o0.y = pi*p0.y*(a0.y + (f - cc0.y));
        o0.z = pi*p0.z*(a0.z + (f - cc0.z)); o0.w = pi*p0.w*(a0.w + (f - cc0.w));
        o1.x = pi*p1.x*(a1.x + (f - cc1.x)); o1.y = pi*p1.y*(a1.y + (f - cc1.y));
        o1.z = pi*p1.z*(a1.z + (f - cc1.z)); o1.w = pi*p1.w*(a1.w + (f - cc1.w));
        *(float4*)&orow[4 * l] = o0;
        *(float4*)&orow[256 + 4 * l] = o1;
    }
}

extern "C" void kernel_launch(void* const* d_in, const int* in_sizes, int n_in,
                              void* d_out, int out_size, void* d_ws, size_t ws_size,
                              hipStream_t stream) {
    (void)in_sizes; (void)n_in; (void)out_size;
    const float* mu    = (const float*)d_in[0];
    const float* Sigma = (const float*)d_in[1];
    float* p_out = (float*)d_out;
    float* S_out = (float*)d_out + (size_t)256 * FDIM;

    if (ws_size >= (size_t)WS_FLOATS * sizeof(float)) {
        float* ws = (float*)d_ws;
        hipLaunchKernelGGL(k1_rc,   dim3(2048), dim3(256), 0, stream, mu, Sigma, p_out, ws);
        hipLaunchKernelGGL(k2b_cs,  dim3(256),  dim3(512), 0, stream, p_out, ws);
        hipLaunchKernelGGL(k3_out,  dim3(2048), dim3(256), 0, stream, Sigma, p_out, ws, S_out);
    } else {
        hipLaunchKernelGGL(rvsoftmax_fused, dim3(256), dim3(1024), 0, stream,
                           mu, Sigma, p_out, S_out);
    }
}